// Round 7
// baseline (35.449 us; speedup 1.0000x reference)
//
#include <hip/hip_runtime.h>
#include <hip/hip_bf16.h>

// Problem constants (from reference)
#define BB 4
#define T1 16
#define T2 32
#define TPn 8
#define Hh 16
#define Kk 64
#define Mm 2049   // 2*H*K + 1
#define NT2B 8    // t2 values handled per block (T2/4)

typedef float  floatx4 __attribute__((ext_vector_type(4)));
typedef int    intx4   __attribute__((ext_vector_type(4)));

// Output: ct_val [B,T1,T2,M,TP] fp32
// ct_val = (dis_sum[b,t1,t2] - dis_sta[b,t1,t2,tp] + dis_cnc[b,t1,t2,m,tp]) / TP
// distance(c1,c2,v) = sgn(c1)*sgn(c2)*(1 - s)*v, s = table[|c1|^|c2|]
// Reference table semantics (verified R3, absmax 3.7e-9): f32 log(x)/log(2) is
// exact at x+1=2^k for all k except k=13,15 (rounds one ulp low => floor=k-1):
//   16*(1-s) = __clz(x+1) - 16 + (x==8191 || x==32767)
// NOTE (R6 lesson): the "one mask" form ((x+1)&0xFFFF5FFF)==0 is WRONG — it
// also accepts x+1=0xA000 (both bits set). Keep the exact comparisons.

__device__ __forceinline__ float omss16(int x) {
    int c = __clz(x + 1) - 16;
    if (x == 8191 || x == 32767) c += 1;
    return (float)c;
}

__global__ __launch_bounds__(256)
void critigraph_kernel(const int* __restrict__ sta_loc,   // [B,T1,TP]
                       const int* __restrict__ pos_loc,   // [B,T2,TP]
                       const float* __restrict__ val_n,   // [B,T1,T2]
                       const int* __restrict__ rand_raw,  // [B*T1,H,K,TP]
                       const int* __restrict__ perm,      // [M]
                       float* __restrict__ out)           // [B,T1,T2,M,TP]
{
    const int bt  = blockIdx.x;        // b*T1 + t1
    const int b   = bt / T1;
    const int mc  = blockIdx.y;        // m chunk of 128 (0..16)
    const int t2q = blockIdx.z;        // t2 quarter (0..3), 8 t2 each
    const int tid = threadIdx.x;

    __shared__ __align__(16) int   s_pabs[NT2B * TPn];   // |pos|
    __shared__ __align__(16) float s_vs8[NT2B * TPn];    // sgn(pos)*val/8
    __shared__ __align__(16) float s_base8[NT2B * TPn];  // (dis_sum - dis_sta)/8
    __shared__ float s_dis[NT2B * TPn];                  // dis_sta (temp)
    __shared__ float s_sum[NT2B];                        // dis_sum per t2
    __shared__ int   s_ori[TPn];                         // |sta|

    if (tid < TPn) {
        int sv = sta_loc[bt * TPn + tid];
        s_ori[tid] = sv < 0 ? -sv : sv;
    }
    if (tid < NT2B * TPn) {
        const int t2l = tid >> 3;
        const int tp  = tid & 7;
        const int t2  = t2q * NT2B + t2l;
        int pv = pos_loc[(b * T2 + t2) * TPn + tp];
        int pa = pv < 0 ? -pv : pv;
        float psgn = (pv >= 0) ? 1.0f : -1.0f;
        int sv = sta_loc[bt * TPn + tp];
        int sa = sv < 0 ? -sv : sv;
        float ssgn = (sv >= 0) ? 1.0f : -1.0f;
        float v = val_n[bt * T2 + t2];
        int x = sa ^ pa;
        s_dis[tid]  = ssgn * psgn * (omss16(x) * 0.0625f) * v;
        s_pabs[tid] = pa;
        s_vs8[tid]  = psgn * v * 0.125f;
    }
    __syncthreads();
    if (tid < NT2B) {
        const float* d = &s_dis[tid * TPn];
        float acc = 0.0f;
        #pragma unroll
        for (int tp = 0; tp < TPn; ++tp) acc += d[tp];
        s_sum[tid] = acc;
    }
    __syncthreads();
    if (tid < NT2B * TPn) {
        s_base8[tid] = (s_sum[tid >> 3] - s_dis[tid]) * 0.125f;
    }
    __syncthreads();

    const int m = mc * 128 + (tid >> 1);
    if (m >= Mm) return;
    const int q4 = (tid & 1) * 4;          // which half of the 8 tp's

    // ---- build candidate coordinate for tp in [q4, q4+4)
    int   a[4];
    float sg16[4];
    const int pm = perm[m];
    if (pm == Hh * Kk) {   // == 1024: the original coordinate
        #pragma unroll
        for (int j = 0; j < 4; ++j) { a[j] = s_ori[q4 + j]; sg16[j] = 0.0625f; }
    } else {
        const int r   = (pm < Hh * Kk) ? pm : pm - (Hh * Kk + 1);
        const float ng = (pm < Hh * Kk) ? 0.0625f : -0.0625f;
        const int jj  = r >> 6;           // r / K
        const int k   = r & 63;           // r % K
        const int mb  = (1 << jj) - 1;    // mod 2^jj
        const int flip = 1 << jj;
        const int* rr = rand_raw + ((bt * Hh + jj) * Kk + k) * TPn + q4;
        #pragma unroll
        for (int j = 0; j < 4; ++j) {
            int res = (s_ori[q4 + j] ^ flip) ^ (rr[j] & mb);
            a[j] = res;
            sg16[j] = (res == 0) ? 0.0625f : ng;  // sign(+0)=+1
        }
    }

    // ---- 8 t2 iterations; one fully-coalesced nontemporal 16B store each
    // lane tid writes bytes [tid*16, tid*16+16) of each wave's 1KB span
    float* op = out + ((long long)(bt * T2 + t2q * NT2B) * Mm + m) * TPn + q4;
    #pragma unroll
    for (int t2l = 0; t2l < NT2B; ++t2l) {
        const int idx = t2l * TPn + q4;
        const intx4   pv = *(const intx4*)&s_pabs[idx];
        const floatx4 vs = *(const floatx4*)&s_vs8[idx];
        const floatx4 bs = *(const floatx4*)&s_base8[idx];
        floatx4 o;
        o.x = fmaf(omss16(a[0] ^ pv.x) * sg16[0], vs.x, bs.x);
        o.y = fmaf(omss16(a[1] ^ pv.y) * sg16[1], vs.y, bs.y);
        o.z = fmaf(omss16(a[2] ^ pv.z) * sg16[2], vs.z, bs.z);
        o.w = fmaf(omss16(a[3] ^ pv.w) * sg16[3], vs.w, bs.w);
        __builtin_nontemporal_store(o, (floatx4*)(op + (long long)t2l * (Mm * TPn)));
    }
}

extern "C" void kernel_launch(void* const* d_in, const int* in_sizes, int n_in,
                              void* d_out, int out_size, void* d_ws, size_t ws_size,
                              hipStream_t stream) {
    const int*   sta_loc  = (const int*)d_in[0];
    const int*   pos_loc  = (const int*)d_in[1];
    const float* val_n    = (const float*)d_in[2];
    const int*   rand_raw = (const int*)d_in[3];
    const int*   perm     = (const int*)d_in[4];
    float* out = (float*)d_out;

    dim3 grid(BB * T1, (Mm + 127) / 128, 4);   // (64, 17, 4) = 4352 blocks
    critigraph_kernel<<<grid, 256, 0, stream>>>(sta_loc, pos_loc, val_n,
                                                rand_raw, perm, out);
}

// Round 8
// 32.528 us; speedup vs baseline: 1.0898x; 1.0898x over previous
//
#include <hip/hip_runtime.h>
#include <hip/hip_bf16.h>

// Problem constants (from reference)
#define BB 4
#define T1 16
#define T2 32
#define TPn 8
#define Hh 16
#define Kk 64
#define Mm 2049   // 2*H*K + 1
#define NT2B 16   // t2 values handled per block (T2/2)

typedef float  floatx4 __attribute__((ext_vector_type(4)));
typedef int    intx4   __attribute__((ext_vector_type(4)));

// Output: ct_val [B,T1,T2,M,TP] fp32
// ct_val = (dis_sum[b,t1,t2] - dis_sta[b,t1,t2,tp] + dis_cnc[b,t1,t2,m,tp]) / TP
// distance(c1,c2,v) = sgn(c1)*sgn(c2)*(1 - s)*v, s = table[|c1|^|c2|]
// Reference table semantics (verified R3, absmax 3.7e-9): f32 log(x)/log(2) is
// exact at x+1=2^k for all k except k=13,15 (rounds one ulp low => floor=k-1):
//   16*(1-s) = __clz(x+1) - 16 + (x==8191 || x==32767)
// R6 lesson: the one-mask form ((x+1)&0xFFFF5FFF)==0 is WRONG (accepts 0xA000).
// R7 lesson: nontemporal stores REGRESS (35.4 vs 30.2 us) — L2 write-combining
// helps this store stream; keep plain stores.

__device__ __forceinline__ float omss16(int x) {
    int c = __clz(x + 1) - 16;
    if (x == 8191 || x == 32767) c += 1;
    return (float)c;
}

__global__ __launch_bounds__(256)
void critigraph_kernel(const int* __restrict__ sta_loc,   // [B,T1,TP]
                       const int* __restrict__ pos_loc,   // [B,T2,TP]
                       const float* __restrict__ val_n,   // [B,T1,T2]
                       const int* __restrict__ rand_raw,  // [B*T1,H,K,TP]
                       const int* __restrict__ perm,      // [M]
                       float* __restrict__ out)           // [B,T1,T2,M,TP]
{
    const int bt  = blockIdx.x;        // b*T1 + t1
    const int b   = bt / T1;
    const int mc  = blockIdx.y;        // m chunk of 128 (0..16)
    const int t2q = blockIdx.z;        // t2 half (0..1), 16 t2 each
    const int tid = threadIdx.x;

    const int m  = mc * 128 + (tid >> 1);
    const int q4 = (tid & 1) * 4;      // which half of the 8 tp's
    const bool mok = (m < Mm);

    // ---- hoist the scattered gathers: issue before the LDS preamble so their
    // latency hides under the barrier phase
    const int pm = mok ? perm[m] : Hh * Kk;
    int rrv[4] = {0, 0, 0, 0};
    int jj = 0;
    bool isori = (pm == Hh * Kk);
    if (!isori) {
        const int r = (pm < Hh * Kk) ? pm : pm - (Hh * Kk + 1);
        jj = r >> 6;
        const int k = r & 63;
        const int* rr = rand_raw + ((bt * Hh + jj) * Kk + k) * TPn + q4;
        #pragma unroll
        for (int j = 0; j < 4; ++j) rrv[j] = rr[j];
    }

    __shared__ __align__(16) int   s_pabs[NT2B * TPn];   // |pos|
    __shared__ __align__(16) float s_vs8[NT2B * TPn];    // sgn(pos)*val/8
    __shared__ __align__(16) float s_base8[NT2B * TPn];  // (dis_sum - dis_sta)/8
    __shared__ float s_dis[NT2B * TPn];                  // dis_sta (temp)
    __shared__ float s_sum[NT2B];                        // dis_sum per t2
    __shared__ int   s_ori[TPn];                         // |sta|

    if (tid < TPn) {
        int sv = sta_loc[bt * TPn + tid];
        s_ori[tid] = sv < 0 ? -sv : sv;
    }
    if (tid < NT2B * TPn) {
        const int t2l = tid >> 3;
        const int tp  = tid & 7;
        const int t2  = t2q * NT2B + t2l;
        int pv = pos_loc[(b * T2 + t2) * TPn + tp];
        int pa = pv < 0 ? -pv : pv;
        float psgn = (pv >= 0) ? 1.0f : -1.0f;
        int sv = sta_loc[bt * TPn + tp];
        int sa = sv < 0 ? -sv : sv;
        float ssgn = (sv >= 0) ? 1.0f : -1.0f;
        float v = val_n[bt * T2 + t2];
        int x = sa ^ pa;
        s_dis[tid]  = ssgn * psgn * (omss16(x) * 0.0625f) * v;
        s_pabs[tid] = pa;
        s_vs8[tid]  = psgn * v * 0.125f;
    }
    __syncthreads();
    if (tid < NT2B) {
        const float* d = &s_dis[tid * TPn];
        float acc = 0.0f;
        #pragma unroll
        for (int tp = 0; tp < TPn; ++tp) acc += d[tp];
        s_sum[tid] = acc;
    }
    __syncthreads();
    if (tid < NT2B * TPn) {
        s_base8[tid] = (s_sum[tid >> 3] - s_dis[tid]) * 0.125f;
    }
    __syncthreads();

    if (!mok) return;

    // ---- build candidate coordinate for tp in [q4, q4+4)
    int   a[4];
    float sg16[4];
    if (isori) {
        #pragma unroll
        for (int j = 0; j < 4; ++j) { a[j] = s_ori[q4 + j]; sg16[j] = 0.0625f; }
    } else {
        const float ng = (pm < Hh * Kk) ? 0.0625f : -0.0625f;
        const int mb   = (1 << jj) - 1;   // mod 2^jj
        const int flip = 1 << jj;
        #pragma unroll
        for (int j = 0; j < 4; ++j) {
            int res = (s_ori[q4 + j] ^ flip) ^ (rrv[j] & mb);
            a[j] = res;
            sg16[j] = (res == 0) ? 0.0625f : ng;  // sign(+0)=+1
        }
    }

    // ---- 16 t2 iterations; one fully-coalesced 16B store each
    // lane tid writes bytes [tid*16, tid*16+16) of each wave's 1KB span
    float* op = out + ((long long)(bt * T2 + t2q * NT2B) * Mm + m) * TPn + q4;
    #pragma unroll
    for (int t2l = 0; t2l < NT2B; ++t2l) {
        const int idx = t2l * TPn + q4;
        const intx4   pv = *(const intx4*)&s_pabs[idx];
        const floatx4 vs = *(const floatx4*)&s_vs8[idx];
        const floatx4 bs = *(const floatx4*)&s_base8[idx];
        floatx4 o;
        o.x = fmaf(omss16(a[0] ^ pv.x) * sg16[0], vs.x, bs.x);
        o.y = fmaf(omss16(a[1] ^ pv.y) * sg16[1], vs.y, bs.y);
        o.z = fmaf(omss16(a[2] ^ pv.z) * sg16[2], vs.z, bs.z);
        o.w = fmaf(omss16(a[3] ^ pv.w) * sg16[3], vs.w, bs.w);
        *(floatx4*)(op + (long long)t2l * (Mm * TPn)) = o;
    }
}

extern "C" void kernel_launch(void* const* d_in, const int* in_sizes, int n_in,
                              void* d_out, int out_size, void* d_ws, size_t ws_size,
                              hipStream_t stream) {
    const int*   sta_loc  = (const int*)d_in[0];
    const int*   pos_loc  = (const int*)d_in[1];
    const float* val_n    = (const float*)d_in[2];
    const int*   rand_raw = (const int*)d_in[3];
    const int*   perm     = (const int*)d_in[4];
    float* out = (float*)d_out;

    dim3 grid(BB * T1, (Mm + 127) / 128, 2);   // (64, 17, 2) = 2176 blocks
    critigraph_kernel<<<grid, 256, 0, stream>>>(sta_loc, pos_loc, val_n,
                                                rand_raw, perm, out);
}